// Round 5
// baseline (273.677 us; speedup 1.0000x reference)
//
#include <hip/hip_runtime.h>
#include <hip/hip_bf16.h>
#include <math.h>

#define DTC 0.01f

typedef __attribute__((ext_vector_type(8))) short short8;   // 8 x bf16 (4 VGPRs)
typedef __attribute__((ext_vector_type(4))) float f32x4;    // MFMA C/D
typedef unsigned short bf16raw;

__device__ __forceinline__ bf16raw f2bf(float f){
  union { unsigned u; float f; } v; v.f = f;
  unsigned r = v.u + 0x7FFF + ((v.u >> 16) & 1u);   // round-to-nearest-even
  return (bf16raw)(r >> 16);
}

// Load 8 consecutive fp32, round to 8 bf16.
__device__ __forceinline__ short8 ld8f(const float* __restrict__ p){
  float4 a = *(const float4*)p;
  float4 b = *(const float4*)(p + 4);
  short8 r;
  r[0] = (short)f2bf(a.x); r[1] = (short)f2bf(a.y);
  r[2] = (short)f2bf(a.z); r[3] = (short)f2bf(a.w);
  r[4] = (short)f2bf(b.x); r[5] = (short)f2bf(b.y);
  r[6] = (short)f2bf(b.z); r[7] = (short)f2bf(b.w);
  return r;
}

// ---------------------------------------------------------------------------
// Async-stage ITERS*16 rows x 32 bf16 (k-contiguous) -> LDS [row][32].
// Per instr: 64 lanes x 16B = 16 rows; LDS dest = wave-uniform base + lane*16B.
// ---------------------------------------------------------------------------
template<int ITERS>
__device__ __forceinline__ void stage_async(const bf16raw* __restrict__ src, long ld,
                                            long row0, int k0, bf16raw* lds,
                                            int wave, int lane){
#pragma unroll
  for (int i = 0; i < ITERS; ++i){
    int r0 = (wave*ITERS + i) * 16;
    long row = row0 + r0 + (lane >> 2);
    const bf16raw* gp = src + row*ld + k0 + (lane & 3)*8;
    bf16raw* lp = lds + r0*32;
    __builtin_amdgcn_global_load_lds((const __attribute__((address_space(1))) void*)gp,
                                     (__attribute__((address_space(3))) void*)lp,
                                     16, 0, 0);
  }
}

// One BK=32 step: 4 A-frags + NI B-frags (ds_read_b128) + 4*NI MFMA.
// A-operand: lane holds A[m=lane&15][k=quad*8+j]; C/D: col=lane&15, row=quad*4+reg.
template<int NI>
__device__ __forceinline__ void mma_tile(const bf16raw* Alds, const bf16raw* Blds,
                                         f32x4 acc[4][NI], int wm, int wn, int quad, int t16){
  short8 af[4], bfr[NI];
#pragma unroll
  for (int mi = 0; mi < 4; ++mi)
    af[mi] = *(const short8*)(Alds + (wm*64 + mi*16 + t16)*32 + quad*8);
#pragma unroll
  for (int ni = 0; ni < NI; ++ni)
    bfr[ni] = *(const short8*)(Blds + (wn*(NI*16) + ni*16 + t16)*32 + quad*8);
#pragma unroll
  for (int mi = 0; mi < 4; ++mi)
#pragma unroll
    for (int ni = 0; ni < NI; ++ni)
      acc[mi][ni] = __builtin_amdgcn_mfma_f32_16x16x32_bf16(af[mi], bfr[ni], acc[mi][ni], 0, 0, 0);
}

// ---------------------------------------------------------------------------
// Prep (weights only): fp32 -> bf16 for [W_omega|W_zeta|W_B] concat, C, D_mat.
// 180224 groups of 8 = 704 blocks x 256.
// ---------------------------------------------------------------------------
extern "C" __global__ void k_prep(const float* __restrict__ Wom,
    const float* __restrict__ Wze, const float* __restrict__ WB,
    const float* __restrict__ Cm, const float* __restrict__ Dm,
    bf16raw* __restrict__ Wcat, bf16raw* __restrict__ C_bf,
    bf16raw* __restrict__ Dm_bf){
  long g = (long)blockIdx.x * 256 + threadIdx.x;
  const float* src; bf16raw* dst; long o;
  if      (g <  8192){ src = Wom; dst = Wcat;          o = g; }
  else if (g < 16384){ src = Wze; dst = Wcat + 65536;  o = g - 8192; }
  else if (g < 32768){ src = WB;  dst = Wcat + 131072; o = g - 16384; }
  else if (g < 49152){ src = Cm;  dst = C_bf;          o = g - 32768; }
  else               { src = Dm;  dst = Dm_bf;         o = g - 49152; }
  *(short8*)(dst + o*8) = ld8f(src + o*8);
}

// ---------------------------------------------------------------------------
// K1: P[bt][n] = sum_d u[bt][d]*Wcat[n][d] (16384x256, K=1024), fp32 out.
// Fused: reads fp32 u, converts in-reg, side-writes u_bf (blockIdx.x==0 only).
// ---------------------------------------------------------------------------
extern "C" __global__ __launch_bounds__(256) void k_gemm_p(
    const float* __restrict__ u, const bf16raw* __restrict__ Wcat,
    bf16raw* __restrict__ u_bf, float* __restrict__ P){
  __shared__ __align__(16) bf16raw Alds[128*32];
  __shared__ __align__(16) bf16raw Blds[128*32];
  int tid = threadIdx.x, wave = tid >> 6, lane = tid & 63;
  int quad = lane >> 4, t16 = lane & 15;
  int wm = wave >> 1, wn = wave & 1;
  long row0 = (long)blockIdx.y * 128;
  int  col0 = blockIdx.x * 128;
  int srow = tid >> 2, sk = (tid & 3) * 8;
  bool writer = (blockIdx.x == 0);
  f32x4 acc[4][4] = {};
  for (int kt = 0; kt < 32; ++kt){
    int k0 = kt*32;
    short8 a0 = ld8f(u + (row0 + srow     )*1024 + k0 + sk);
    short8 a1 = ld8f(u + (row0 + srow + 64)*1024 + k0 + sk);
    __syncthreads();
    *(short8*)(Alds + (srow     )*32 + sk) = a0;
    *(short8*)(Alds + (srow + 64)*32 + sk) = a1;
    stage_async<2>(Wcat, 1024, col0, k0, Blds, wave, lane);
    if (writer){
      *(short8*)(u_bf + (row0 + srow     )*1024 + k0 + sk) = a0;
      *(short8*)(u_bf + (row0 + srow + 64)*1024 + k0 + sk) = a1;
    }
    __syncthreads();
    mma_tile<4>(Alds, Blds, acc, wm, wn, quad, t16);
  }
#pragma unroll
  for (int mi = 0; mi < 4; ++mi)
#pragma unroll
    for (int ni = 0; ni < 4; ++ni)
#pragma unroll
      for (int r = 0; r < 4; ++r){
        long grow = row0 + wm*64 + mi*16 + quad*4 + r;
        int  gcol = col0 + wn*64 + ni*16 + t16;
        P[grow*256 + gcol] = acc[mi][ni][r];
      }
}

// ---------------------------------------------------------------------------
// Fused coef + chunk-summary (scan pass 1). Block = (chunk c, batch b).
// Phase A: 256 threads compute coef for 32t x 64m; write Coef + LDS.
// Phase B: threads 0..63 (one per m) serially reduce 32 steps from LDS,
// writing chunk transition CMt / affine CVt in series-major layout.
// ---------------------------------------------------------------------------
extern "C" __global__ __launch_bounds__(256) void k_coefscan1(
    const float* __restrict__ P, const float* __restrict__ b_om,
    const float* __restrict__ b_ze, const float* __restrict__ b_B,
    float4* __restrict__ Coef, float4* __restrict__ CMt,
    float2* __restrict__ CVt){
  __shared__ float4 lds_c[2048];    // 32 KB: [t][m]
  int tid = threadIdx.x;
  int c = blockIdx.x;               // 0..127
  int b = blockIdx.y;               // 0..3
  int t = tid >> 3;                 // 0..31
  int m0 = (tid & 7) * 8;
  long bt = (long)b*4096 + c*32 + t;
  const float* row = P + bt*256;
#pragma unroll
  for (int j = 0; j < 8; ++j){
    int m = m0 + j;
    float wo = row[m]       + b_om[m];
    float wz = row[64 + m]  + b_ze[m];
    float fz = row[128 + m] + b_B[m];
    float fy = row[192 + m] + b_B[64 + m];
    float sp = (wo > 20.f) ? wo : log1pf(expf(wo));
    float omega = fminf(fmaxf(sp, 1e-4f), 100.f);
    float A = omega * omega;
    float S = 1.f / (1.f + DTC*DTC*A);
    float zeta = 1.f / (1.f + expf(-wz));
    float p = (1.f - zeta) * S;
    float q = p * DTC * A;
    float4 f4 = make_float4(p, q, fz, fy);
    lds_c[t*64 + m] = f4;
    Coef[bt*64 + m] = f4;
  }
  __syncthreads();
  if (tid < 64){
    int m = tid;
    float m00=1.f, m01=0.f, m10=0.f, m11=0.f, vz=0.f, vy=0.f;
#pragma unroll 4
    for (int tt = 0; tt < 32; ++tt){
      float4 f = lds_c[tt*64 + m];
      float p = f.x, q = f.y;
      float nvz = p*vz - q*vy + f.z;
      float nvy = DTC*p*vz + p*vy + f.w;
      vz = nvz; vy = nvy;
      float n00 = p*m00 - q*m10;
      float n01 = p*m01 - q*m11;
      float n10 = DTC*p*m00 + p*m10;
      float n11 = DTC*p*m01 + p*m11;
      m00=n00; m01=n01; m10=n10; m11=n11;
    }
    int s = b*64 + m;
    CMt[s*128 + c] = make_float4(m00, m01, m10, m11);
    CVt[s*128 + c] = make_float2(vz, vy);
  }
}

// ---------------------------------------------------------------------------
// Scan pass 2: Kogge-Stone over 128 chunk summaries, one block per series s.
// Composition (A after B): M = Ma*Mb, v = Ma*vb + va. Exclusive prefix -> XIn.
// ---------------------------------------------------------------------------
extern "C" __global__ __launch_bounds__(128) void k_scan2p(
    const float4* __restrict__ CMt, const float2* __restrict__ CVt,
    float2* __restrict__ XIn){
  __shared__ float4 Ml[128];
  __shared__ float2 Vl[128];
  int c = threadIdx.x, s = blockIdx.x;
  Ml[c] = CMt[s*128 + c];
  Vl[c] = CVt[s*128 + c];
  __syncthreads();
  for (int off = 1; off < 128; off <<= 1){
    float4 Mb; float2 Vb;
    if (c >= off){ Mb = Ml[c-off]; Vb = Vl[c-off]; }
    __syncthreads();
    if (c >= off){
      float4 Ma = Ml[c]; float2 Va = Vl[c];
      float4 Mn; float2 Vn;
      Mn.x = Ma.x*Mb.x + Ma.y*Mb.z;
      Mn.y = Ma.x*Mb.y + Ma.y*Mb.w;
      Mn.z = Ma.z*Mb.x + Ma.w*Mb.z;
      Mn.w = Ma.z*Mb.y + Ma.w*Mb.w;
      Vn.x = Ma.x*Vb.x + Ma.y*Vb.y + Va.x;
      Vn.y = Ma.z*Vb.x + Ma.w*Vb.y + Va.y;
      Ml[c] = Mn; Vl[c] = Vn;
    }
    __syncthreads();
  }
  float2 xin = (c == 0) ? make_float2(0.f, 0.f) : Vl[c-1];
  XIn[c*256 + s] = xin;
}

// ---------------------------------------------------------------------------
// Scan pass 3: replay each chunk from exact incoming state; emit Xs bf16.
// ---------------------------------------------------------------------------
extern "C" __global__ void k_scan3(const float4* __restrict__ Coef,
    const float2* __restrict__ XIn, bf16raw* __restrict__ Xs){
  int tid = threadIdx.x, c = blockIdx.x;
  int b = tid >> 6, m = tid & 63;
  const float4* cf = Coef + ((size_t)b*4096 + c*32)*64 + m;
  float2 x0 = XIn[c*256 + tid];
  float xz = x0.x, xy = x0.y;
  bf16raw* xp = Xs + ((size_t)b*4096 + c*32)*128 + m;
#pragma unroll 4
  for (int t = 0; t < 32; ++t){
    float4 f = cf[t*64];
    float p = f.x, q = f.y;
    float nz = p*xz - q*xy + f.z;
    float ny = DTC*p*xz + p*xy + f.w;
    xz = nz; xy = ny;
    xp[t*128]      = f2bf(xz);   // z part: n = m
    xp[t*128 + 64] = f2bf(xy);   // y part: n = 64 + m
  }
}

// ---------------------------------------------------------------------------
// K4: out[bt][d] = sum_n Xs[bt][n]*C[d][n] + sum_e u[bt][e]*Dm[d][e], fp32 out.
// 128x128 tile (sweet spot per tile-space data), grid 8x128 -> 4 blocks/CU.
// ---------------------------------------------------------------------------
extern "C" __global__ __launch_bounds__(256) void k_gemm_out(
    const bf16raw* __restrict__ Xs, const bf16raw* __restrict__ u_bf,
    const bf16raw* __restrict__ C_bf, const bf16raw* __restrict__ Dm_bf,
    float* __restrict__ out){
  __shared__ __align__(16) bf16raw Alds[128*32];
  __shared__ __align__(16) bf16raw Blds[128*32];
  int tid = threadIdx.x, wave = tid >> 6, lane = tid & 63;
  int quad = lane >> 4, t16 = lane & 15;
  int wm = wave >> 1, wn = wave & 1;
  long row0 = (long)blockIdx.y * 128;
  int  col0 = blockIdx.x * 128;
  f32x4 acc[4][4] = {};
  for (int kt = 0; kt < 4; ++kt){            // phase 1: Xs @ C^T (K=128)
    __syncthreads();
    stage_async<2>(Xs,   128, row0, kt*32, Alds, wave, lane);
    stage_async<2>(C_bf, 128, col0, kt*32, Blds, wave, lane);
    __syncthreads();
    mma_tile<4>(Alds, Blds, acc, wm, wn, quad, t16);
  }
  for (int kt = 0; kt < 32; ++kt){           // phase 2: u @ Dm^T (K=1024)
    __syncthreads();
    stage_async<2>(u_bf,  1024, row0, kt*32, Alds, wave, lane);
    stage_async<2>(Dm_bf, 1024, col0, kt*32, Blds, wave, lane);
    __syncthreads();
    mma_tile<4>(Alds, Blds, acc, wm, wn, quad, t16);
  }
#pragma unroll
  for (int mi = 0; mi < 4; ++mi)
#pragma unroll
    for (int ni = 0; ni < 4; ++ni)
#pragma unroll
      for (int r = 0; r < 4; ++r){
        long grow = row0 + wm*64 + mi*16 + quad*4 + r;
        int  gcol = col0 + wn*64 + ni*16 + t16;
        out[grow*1024 + gcol] = acc[mi][ni][r];
      }
}

// ---------------------------------------------------------------------------
extern "C" void kernel_launch(void* const* d_in, const int* in_sizes, int n_in,
                              void* d_out, int out_size, void* d_ws, size_t ws_size,
                              hipStream_t stream){
  const float* u   = (const float*)d_in[0];
  const float* Wom = (const float*)d_in[1];
  const float* bom = (const float*)d_in[2];
  const float* Wze = (const float*)d_in[3];
  const float* bze = (const float*)d_in[4];
  const float* WB  = (const float*)d_in[5];
  const float* bB  = (const float*)d_in[6];
  const float* Cm  = (const float*)d_in[7];
  const float* Dm  = (const float*)d_in[8];
  float* out = (float*)d_out;

  char* ws = (char*)d_ws;
  size_t off = 0;
  bf16raw* u_bf  = (bf16raw*)(ws + off); off += (size_t)16777216*2;    // 32 MB
  bf16raw* Wcat  = (bf16raw*)(ws + off); off += (size_t)262144*2;      // 512 KB
  bf16raw* C_bf  = (bf16raw*)(ws + off); off += (size_t)131072*2;      // 256 KB
  bf16raw* Dm_bf = (bf16raw*)(ws + off); off += (size_t)1048576*2;     // 2 MB
  float*   P     = (float*)  (ws + off);
  bf16raw* Xs    = (bf16raw*)P;          // overlay: P dead after k_coefscan1
  off += (size_t)16384*256*4;                                          // 16 MB
  float4*  Coef  = (float4*) (ws + off); off += (size_t)16384*64*16;   // 16 MB
  float4*  CMt   = (float4*) (ws + off); off += (size_t)256*128*16;    // 512 KB
  float2*  CVt   = (float2*) (ws + off); off += (size_t)256*128*8;     // 256 KB
  float2*  XIn   = (float2*) (ws + off); off += (size_t)128*256*8;     // 256 KB

  k_prep     <<<704, 256, 0, stream>>>(Wom, Wze, WB, Cm, Dm, Wcat, C_bf, Dm_bf);
  k_gemm_p   <<<dim3(2, 128), 256, 0, stream>>>(u, Wcat, u_bf, P);
  k_coefscan1<<<dim3(128, 4), 256, 0, stream>>>(P, bom, bze, bB, Coef, CMt, CVt);
  k_scan2p   <<<256, 128, 0, stream>>>(CMt, CVt, XIn);
  k_scan3    <<<128, 256, 0, stream>>>(Coef, XIn, Xs);
  k_gemm_out <<<dim3(8, 128), 256, 0, stream>>>(Xs, u_bf, C_bf, Dm_bf, out);
}